// Round 8
// baseline (363.881 us; speedup 1.0000x reference)
//
#include <hip/hip_runtime.h>
#include <math.h>

#define L 2048
#define D 1024
#define H 16
#define Z 64
#define HZ 1024

typedef __bf16 bf16x8 __attribute__((ext_vector_type(8)));
typedef float f32x4 __attribute__((ext_vector_type(4)));
typedef float f32x16 __attribute__((ext_vector_type(16)));

#if __has_builtin(__builtin_amdgcn_exp2f)
#define EXP2(x) __builtin_amdgcn_exp2f(x)
#else
#define EXP2(x) exp2f(x)
#endif

// ---------------------------------------------------------------------------
// Async global->LDS DMA, 16B per lane (lane i lands at base + i*16).
// ---------------------------------------------------------------------------
__device__ __forceinline__ void async_ld16(const void* g, void* l) {
  __builtin_amdgcn_global_load_lds(
      (const __attribute__((address_space(1))) uint32_t*)(uintptr_t)g,
      (__attribute__((address_space(3))) uint32_t*)(uint32_t)(uintptr_t)l,
      16, 0, 0);
}

// ---------------------------------------------------------------------------
// Fragment-ordered tile staging. 1KB region per (16-row group, 32-col half):
// region = (r>>4)*2 + (cc>>2), slot = (r&15) + (cc&3)*16  (cc = 16B chunk).
// ---------------------------------------------------------------------------
template<int NPIECE>
__device__ __forceinline__ void stage_async(const __bf16* __restrict__ g,
                                            int gstride, char* lds, int tid) {
  const int l = tid & 63, w = tid >> 6;
#pragma unroll
  for (int it = 0; it < NPIECE; ++it) {
    const int region = it * 4 + w;
    const int r = ((region >> 1) << 4) + (l & 15);
    const int c = ((region & 1) << 2) + (l >> 4);
    async_ld16(g + (size_t)r * gstride + c * 8, lds + (region << 10));
  }
}

__device__ __forceinline__ bf16x8 rfrag(const char* lds, int row, int cc) {
  const int region = ((row >> 4) << 1) + (cc >> 2);
  const int slot = (row & 15) + ((cc & 3) << 4);
  return *(const bf16x8*)(lds + region * 1024 + slot * 16);
}

// ---------------------------------------------------------------------------
// fp32 -> bf16 flat convert (n4 = n/4)
// ---------------------------------------------------------------------------
__global__ __launch_bounds__(256) void cvt_kernel(const float* __restrict__ s,
                                                  __bf16* __restrict__ d, int n4) {
  int i = blockIdx.x * 256 + threadIdx.x;
  if (i < n4) {
    float4 v = ((const float4*)s)[i];
    union { __bf16 h[4]; uint2 u; } o;
    o.h[0] = (__bf16)v.x; o.h[1] = (__bf16)v.y;
    o.h[2] = (__bf16)v.z; o.h[3] = (__bf16)v.w;
    ((uint2*)d)[i] = o.u;
  }
}

// ---------------------------------------------------------------------------
// W (fp32) -> Wb (bf16 straight) + Wt (bf16 transposed)
// ---------------------------------------------------------------------------
__global__ __launch_bounds__(256) void wt_kernel(
    const float* __restrict__ Wk, const float* __restrict__ Wq,
    __bf16* __restrict__ Wkb, __bf16* __restrict__ Wqb,
    __bf16* __restrict__ Wkt, __bf16* __restrict__ Wqt) {
  const float* W = blockIdx.z ? Wq : Wk;
  __bf16* Wb = blockIdx.z ? Wqb : Wkb;
  __bf16* Wt = blockIdx.z ? Wqt : Wkt;
  __shared__ __bf16 tile[64][65];
  const int r0 = blockIdx.y * 64, c0 = blockIdx.x * 64;
  const int c = threadIdx.x & 63, rb = threadIdx.x >> 6;
#pragma unroll
  for (int i = 0; i < 16; ++i) {
    int r = rb + i * 4;
    __bf16 v = (__bf16)W[(size_t)(r0 + r) * D + c0 + c];
    tile[r][c] = v;
    Wb[(size_t)(r0 + r) * D + c0 + c] = v;
  }
  __syncthreads();
#pragma unroll
  for (int i = 0; i < 16; ++i) {
    int r = rb + i * 4;
    Wt[(size_t)(c0 + r) * HZ + r0 + c] = tile[c][r];
  }
}

// l-permutation for the transposed kp/qp buffers: within each 16-l group,
// 4-el pieces stored in order [0-3, 8-11, 4-7, 12-15].
__device__ __forceinline__ int lperm(int mg) {
  const int off = mg & 15;
  return (mg & ~15) | (((off >> 2) & 1) << 3) | (((off >> 3) & 1) << 2);
}

// ---------------------------------------------------------------------------
// proj: kp/qp[bh][l][z] = SCALE * sum_d x*W   (SCALE = sqrt(beta*log2e));
// kpt/qpt[bh][z][l] = UNSCALED (l-permuted).
// 128x128 tile, 4 waves, 32x32x16 MFMA, BK=64, async double-buffered LDS.
// ---------------------------------------------------------------------------
__global__ __launch_bounds__(256, 2) void proj_kernel(
    const __bf16* __restrict__ xb, const __bf16* __restrict__ Wkb,
    const __bf16* __restrict__ Wqb, const float* __restrict__ beta_p,
    __bf16* __restrict__ kp, __bf16* __restrict__ qp,
    __bf16* __restrict__ kpt, __bf16* __restrict__ qpt) {
  const __bf16* __restrict__ Wb = blockIdx.z ? Wqb : Wkb;
  __bf16* __restrict__ outn = blockIdx.z ? qp : kp;
  __bf16* __restrict__ outt = blockIdx.z ? qpt : kpt;
  const int n0 = blockIdx.x * 128, m0 = blockIdx.y * 128;
  const int tid = threadIdx.x, l = tid & 63, w = tid >> 6;
  const int l31 = l & 31, hi = l >> 5;
  const int mh = w >> 1, nh = w & 1;
  const float ab = beta_p[0] * 1.44269504f;
  const float ssc = sqrtf(fabsf(ab));
  const float sc = blockIdx.z ? ssc : ((ab < 0.f) ? -ssc : ssc);
  __shared__ __align__(16) char sA[2][16384], sB[2][16384];

  f32x16 acc[2][2];
#pragma unroll
  for (int mi = 0; mi < 2; ++mi)
#pragma unroll
    for (int ni = 0; ni < 2; ++ni)
#pragma unroll
      for (int i = 0; i < 16; ++i) acc[mi][ni][i] = 0.f;

  const __bf16* __restrict__ Abase = xb + (size_t)m0 * D;
  const __bf16* __restrict__ Bbase = Wb + (size_t)n0 * D;
  stage_async<4>(Abase, D, sA[0], tid);
  stage_async<4>(Bbase, D, sB[0], tid);
  __syncthreads();

  for (int k = 0; k < 16; ++k) {
    const int cur = k & 1, nxt = cur ^ 1;
    if (k < 15) {
      stage_async<4>(Abase + (k + 1) * 64, D, sA[nxt], tid);
      stage_async<4>(Bbase + (k + 1) * 64, D, sB[nxt], tid);
    }
#pragma unroll
    for (int ks = 0; ks < 4; ++ks) {
      bf16x8 am[2], bn[2];
#pragma unroll
      for (int mi = 0; mi < 2; ++mi)
        am[mi] = rfrag(sA[cur], mh * 64 + mi * 32 + l31, 2 * ks + hi);
#pragma unroll
      for (int ni = 0; ni < 2; ++ni)
        bn[ni] = rfrag(sB[cur], nh * 64 + ni * 32 + l31, 2 * ks + hi);
#pragma unroll
      for (int mi = 0; mi < 2; ++mi)
#pragma unroll
        for (int ni = 0; ni < 2; ++ni)
          acc[mi][ni] = __builtin_amdgcn_mfma_f32_32x32x16_bf16(
              am[mi], bn[ni], acc[mi][ni], 0, 0, 0);
    }
    __syncthreads();
  }

  const int b = m0 >> 11;
  const int h = (n0 >> 6) + nh;
  const size_t bh = (size_t)b * H + h;
#pragma unroll
  for (int mi = 0; mi < 2; ++mi)
#pragma unroll
    for (int ni = 0; ni < 2; ++ni) {
      const int z = ni * 32 + l31;
#pragma unroll
      for (int rg = 0; rg < 4; ++rg) {
        const int mloc = mh * 64 + mi * 32 + 8 * rg + 4 * hi;
        const int mg = (m0 & (L - 1)) + mloc;
        union { __bf16 hh[4]; uint2 u; } pk;
#pragma unroll
        for (int j = 0; j < 4; ++j) {
          const float v = acc[mi][ni][4 * rg + j];
          pk.hh[j] = (__bf16)v;                                 // unscaled -> T
          outn[(bh * L + mg + j) * Z + z] = (__bf16)(v * sc);   // scaled -> S ops
        }
        *(uint2*)(outt + (bh * Z + z) * L + lperm(mg)) = pk.u;
      }
    }
}

// ---------------------------------------------------------------------------
// grad kernel, cross-barrier pipelined:
//   iter kt: barrier(T_kt landed; DMA'd one full iter ago) -> issue DMA T_{kt+1}
//   -> ds-read bt_kt -> exp on St_kt (computed LAST iter, in regs) -> PV_kt
//   -> St_{kt+1} (av loaded this iter, covered by exp+PV).
// MODE 0: Gkp[q][z] = -(1/li_q) sum_c 2^S[q][c] * qp[c][z]; lse=ln(li)
// MODE 1: Gqp[kq][z] = -sum_q 2^S[q][kq] * kpw[q][z]  (kpw pre-scaled)
// ---------------------------------------------------------------------------
template<int MODE>
__global__ __launch_bounds__(256, 2) void grad_kernel(
    const __bf16* __restrict__ Rg, const __bf16* __restrict__ Sg,
    const __bf16* __restrict__ Tg,
    float* __restrict__ lse, __bf16* __restrict__ Gout) {
  const int bid = blockIdx.x;
  const int slot = bid >> 3;
  const int bh = (bid & 7) * 4 + (slot >> 4);
  const int qt = slot & 15;
  const int tid = threadIdx.x, l = tid & 63, w = tid >> 6;
  const int l31 = l & 31, hi = l >> 5;
  const int q0 = qt * 128 + w * 32;
  __shared__ __align__(16) char sT[2][8192];

  // resident operand as 32x32x16 B-fragments: B[n=l31][k=16ks+8hi+j]
  bf16x8 bres[4];
#pragma unroll
  for (int ks = 0; ks < 4; ++ks)
    bres[ks] = *(const bf16x8*)(
        Rg + ((size_t)bh * L + q0 + l31) * Z + ks * 16 + hi * 8);

  f32x16 pv[2];
#pragma unroll
  for (int zt = 0; zt < 2; ++zt)
#pragma unroll
    for (int i = 0; i < 16; ++i) pv[zt][i] = 0.f;
  float li = 0.f;

  const __bf16* __restrict__ Sbase =
      Sg + (size_t)bh * L * Z + (size_t)l31 * Z + hi * 8;
  const __bf16* __restrict__ Tbase = Tg + (size_t)bh * Z * L;

  // prologue: DMA T0; av tile0; St0 (register-only, no LDS dependency)
  stage_async<2>(Tbase, L, sT[0], tid);
  bf16x8 av[8];
#pragma unroll
  for (int nt = 0; nt < 2; ++nt)
#pragma unroll
    for (int ks = 0; ks < 4; ++ks)
      av[nt * 4 + ks] = *(const bf16x8*)(Sbase + (size_t)(nt * 32) * Z + ks * 16);
  f32x16 st[2];
#pragma unroll
  for (int i = 0; i < 16; ++i) { st[0][i] = 0.f; st[1][i] = 0.f; }
#pragma unroll
  for (int ks = 0; ks < 4; ++ks) {
    st[0] = __builtin_amdgcn_mfma_f32_32x32x16_bf16(av[ks], bres[ks], st[0], 0, 0, 0);
    st[1] = __builtin_amdgcn_mfma_f32_32x32x16_bf16(av[4 + ks], bres[ks], st[1], 0, 0, 0);
  }

  for (int kt = 0; kt < 32; ++kt) {
    const int cur = kt & 1, nxt = cur ^ 1;
    __syncthreads();                       // T_kt guaranteed in sT[cur]
    if (kt < 31) stage_async<2>(Tbase + (kt + 1) * 64, L, sT[nxt], tid);
    // PV B-frags for tile kt
    bf16x8 bt[8];
#pragma unroll
    for (int kc = 0; kc < 4; ++kc) {
      bt[2 * kc]     = rfrag(sT[cur], l31,      2 * kc + hi);
      bt[2 * kc + 1] = rfrag(sT[cur], 32 + l31, 2 * kc + hi);
    }
    // av for tile kt+1 (consumed at end of this iteration)
    if (kt < 31) {
#pragma unroll
      for (int nt = 0; nt < 2; ++nt)
#pragma unroll
        for (int ks = 0; ks < 4; ++ks)
          av[nt * 4 + ks] = *(const bf16x8*)(
              Sbase + (size_t)((kt + 1) * 64 + nt * 32) * Z + ks * 16);
    }
    // P = 2^St_kt (st computed last iteration; fixed max = 0)
    uint32_t P32[2][8];
    float lsn = 0.f;
#pragma unroll
    for (int nt = 0; nt < 2; ++nt)
#pragma unroll
      for (int i = 0; i < 8; ++i) {
        float e0 = EXP2(st[nt][2 * i]);
        float e1 = EXP2(st[nt][2 * i + 1]);
        if (MODE == 0) lsn += e0 + e1;
        union { __bf16 hh[2]; uint32_t u; } pk;
        pk.hh[0] = (__bf16)e0; pk.hh[1] = (__bf16)e1;
        P32[nt][i] = pk.u;
      }
    if (MODE == 0) li += lsn;
    // PV: D[q][z] += P[q][c] * T[c][z]
#pragma unroll
    for (int kc = 0; kc < 4; ++kc) {
      union { uint32_t u[4]; bf16x8 v; } a;
#pragma unroll
      for (int i = 0; i < 4; ++i) a.u[i] = P32[kc >> 1][4 * (kc & 1) + i];
      pv[0] = __builtin_amdgcn_mfma_f32_32x32x16_bf16(a.v, bt[2 * kc], pv[0], 0, 0, 0);
      pv[1] = __builtin_amdgcn_mfma_f32_32x32x16_bf16(a.v, bt[2 * kc + 1], pv[1], 0, 0, 0);
    }
    // St_{kt+1} into st (av covered by exp+PV above)
    if (kt < 31) {
#pragma unroll
      for (int i = 0; i < 16; ++i) { st[0][i] = 0.f; st[1][i] = 0.f; }
#pragma unroll
      for (int ks = 0; ks < 4; ++ks) {
        st[0] = __builtin_amdgcn_mfma_f32_32x32x16_bf16(av[ks], bres[ks], st[0], 0, 0, 0);
        st[1] = __builtin_amdgcn_mfma_f32_32x32x16_bf16(av[4 + ks], bres[ks], st[1], 0, 0, 0);
      }
    }
  }
  if (MODE == 0) li += __shfl_xor(li, 32);
  const int b = bh >> 4, head = bh & (H - 1);
#pragma unroll
  for (int r = 0; r < 16; ++r) {
    const int qoff = (r & 3) + 8 * (r >> 2) + 4 * hi;   // C-layout row
    float scl = 1.f;
    if (MODE == 0)
      scl = 1.f / __int_as_float(
                __builtin_amdgcn_ds_bpermute(4 * qoff, __float_as_int(li)));
    const size_t orow = ((size_t)b * L + q0 + qoff) * HZ + head * Z;
    Gout[orow + l31]      = (__bf16)(-pv[0][r] * scl);
    Gout[orow + 32 + l31] = (__bf16)(-pv[1][r] * scl);
  }
  if (MODE == 0 && hi == 0)
    lse[(size_t)bh * L + q0 + l31] = __logf(li);
}

// ---------------------------------------------------------------------------
// kpt[row][pos] *= exp(-lse[true_l(pos)])  (in place; pos is l-permuted)
// ---------------------------------------------------------------------------
__global__ __launch_bounds__(256) void kscale_kernel(__bf16* __restrict__ kpt,
                                                     const float* __restrict__ lse) {
  int idx = blockIdx.x * 256 + threadIdx.x;
  int row = idx >> 9;                          // bh*64 + z
  int pos4 = (idx & 511) << 2;
  int bh = row >> 6;
  int lbase = (pos4 & ~15) + (((pos4 >> 2) & 1) << 3) + (((pos4 >> 3) & 1) << 2);
  float4 ls = *(const float4*)(lse + (size_t)bh * L + lbase);
  __bf16* p = kpt + (size_t)row * L + pos4;
  union { __bf16 hh[4]; uint2 u; } v;
  v.u = *(uint2*)p;
  v.hh[0] = (__bf16)((float)v.hh[0] * __expf(-ls.x));
  v.hh[1] = (__bf16)((float)v.hh[1] * __expf(-ls.y));
  v.hh[2] = (__bf16)((float)v.hh[2] * __expf(-ls.z));
  v.hh[3] = (__bf16)((float)v.hh[3] * __expf(-ls.w));
  *(uint2*)p = v.u;
}

// ---------------------------------------------------------------------------
// en[b] = -(1/beta) * sum_{h,q} lse[b,h,q]
// ---------------------------------------------------------------------------
__global__ __launch_bounds__(256) void energy_kernel(
    const float* __restrict__ lse_ws, const float* __restrict__ beta_p,
    float* __restrict__ out) {
  const int b = blockIdx.x;
  const float* p = lse_ws + (size_t)b * H * L;
  float sum = 0.f;
  for (int i = threadIdx.x; i < H * L; i += 256) sum += p[i];
#pragma unroll
  for (int off = 1; off < 64; off <<= 1) sum += __shfl_xor(sum, off, 64);
  __shared__ float wsum[4];
  if ((threadIdx.x & 63) == 0) wsum[threadIdx.x >> 6] = sum;
  __syncthreads();
  if (threadIdx.x == 0)
    out[b] = -(wsum[0] + wsum[1] + wsum[2] + wsum[3]) / beta_p[0];
}

// ---------------------------------------------------------------------------
// gx[m][d] = sum_hz Gkp[m][hz]*Wk[hz][d] + Gqp[m][hz]*Wq[hz][d]
// 128x64 tile (grid 16x32 = 512 blocks -> 2 blocks/CU), K=2048 stacked,
// async double-buffered. Wave w owns m-strip w*32, full n=64.
// ---------------------------------------------------------------------------
__global__ __launch_bounds__(256, 2) void gx_kernel(
    const __bf16* __restrict__ Gkp, const __bf16* __restrict__ Gqp,
    const __bf16* __restrict__ Wkt, const __bf16* __restrict__ Wqt,
    float* __restrict__ gx) {
  const int n0 = blockIdx.x * 64, m0 = blockIdx.y * 128;
  const int tid = threadIdx.x, l = tid & 63, w = tid >> 6;
  const int l31 = l & 31, hi = l >> 5;
  __shared__ __align__(16) char sA[2][16384], sB[2][8192];

  f32x16 acc[2];
#pragma unroll
  for (int ni = 0; ni < 2; ++ni)
#pragma unroll
    for (int i = 0; i < 16; ++i) acc[ni][i] = 0.f;

  stage_async<4>(Gkp + (size_t)m0 * HZ, HZ, sA[0], tid);
  stage_async<2>(Wkt + (size_t)n0 * HZ, HZ, sB[0], tid);
  __syncthreads();

  for (int kk = 0; kk < 32; ++kk) {
    const int cur = kk & 1, nxt = cur ^ 1;
    if (kk < 31) {
      const int kn = kk + 1;
      const __bf16* __restrict__ An = (kn < 16 ? Gkp : Gqp);
      const __bf16* __restrict__ Bn = (kn < 16 ? Wkt : Wqt);
      const int k0 = (kn & 15) * 64;
      stage_async<4>(An + (size_t)m0 * HZ + k0, HZ, sA[nxt], tid);
      stage_async<2>(Bn + (size_t)n0 * HZ + k0, HZ, sB[nxt], tid);
    }
#pragma unroll
    for (int ks = 0; ks < 4; ++ks) {
      bf16x8 am = rfrag(sA[cur], w * 32 + l31, 2 * ks + hi);
      bf16x8 bn0 = rfrag(sB[cur], l31, 2 * ks + hi);
      bf16x8 bn1 = rfrag(sB[cur], 32 + l31, 2 * ks + hi);
      acc[0] = __builtin_amdgcn_mfma_f32_32x32x16_bf16(am, bn0, acc[0], 0, 0, 0);
      acc[1] = __builtin_amdgcn_mfma_f32_32x32x16_bf16(am, bn1, acc[1], 0, 0, 0);
    }
    __syncthreads();
  }
#pragma unroll
  for (int ni = 0; ni < 2; ++ni) {
    const int n = n0 + ni * 32 + l31;
#pragma unroll
    for (int r = 0; r < 16; ++r) {
      const int m = m0 + w * 32 + (r & 3) + 8 * (r >> 2) + 4 * hi;
      gx[(size_t)m * D + n] = acc[ni][r];
    }
  }
}

// ---------------------------------------------------------------------------
extern "C" void kernel_launch(void* const* d_in, const int* in_sizes, int n_in,
                              void* d_out, int out_size, void* d_ws, size_t ws_size,
                              hipStream_t stream) {
  const float* x    = (const float*)d_in[0];
  const float* Wq   = (const float*)d_in[1];
  const float* Wk   = (const float*)d_in[2];
  const float* beta = (const float*)d_in[3];
  float* out = (float*)d_out;

  char* ws = (char*)d_ws;
  __bf16* xb  = (__bf16*)(ws);                         // 8 MB
  __bf16* Wkb = (__bf16*)(ws + (8ull  << 20));         // 2 MB
  __bf16* Wqb = (__bf16*)(ws + (10ull << 20));         // 2 MB
  __bf16* Wkt = (__bf16*)(ws + (12ull << 20));         // 2 MB
  __bf16* Wqt = (__bf16*)(ws + (14ull << 20));         // 2 MB
  __bf16* kp  = (__bf16*)(ws + (16ull << 20));         // 8 MB (scaled)
  __bf16* qp  = (__bf16*)(ws + (24ull << 20));         // 8 MB (scaled)
  __bf16* kpt = (__bf16*)(ws + (32ull << 20));         // 8 MB (l-perm, unscaled)
  __bf16* qpt = (__bf16*)(ws + (40ull << 20));         // 8 MB (l-perm, unscaled)
  __bf16* Gkp = (__bf16*)(ws + (48ull << 20));         // 8 MB
  __bf16* Gqp = (__bf16*)(ws + (56ull << 20));         // 8 MB
  float*  lse = (float*)(ws + (64ull << 20));          // 256 KB

  cvt_kernel<<<4096, 256, 0, stream>>>(x, xb, 1048576);
  wt_kernel<<<dim3(16, 16, 2), 256, 0, stream>>>(Wk, Wq, Wkb, Wqb, Wkt, Wqt);
  proj_kernel<<<dim3(8, 32, 2), 256, 0, stream>>>(xb, Wkb, Wqb, beta, kp, qp, kpt, qpt);
  grad_kernel<0><<<512, 256, 0, stream>>>(kp, qp, qpt, lse, Gkp);
  kscale_kernel<<<4096, 256, 0, stream>>>(kpt, lse);
  grad_kernel<1><<<512, 256, 0, stream>>>(qp, kp, kpt, lse, Gqp);
  energy_kernel<<<2, 256, 0, stream>>>(lse, beta, out);
  gx_kernel<<<dim3(16, 32), 256, 0, stream>>>(Gkp, Gqp, Wkt, Wqt, out + 2);
}